// Round 5
// baseline (1016.157 us; speedup 1.0000x reference)
//
#include <hip/hip_runtime.h>
#include <math.h>

// ---- problem constants ----
#define TB        64            // threads per block (main kernel) = 1 wave
#define P         2             // positions per thread
#define KB        8             // codes per k-loop pass
#define NPOS      131072        // B*H*W positions
#define KCODES    512
#define DIM       64
#define HW        4096          // H*W
#define ROWD      17            // float4 per LDS row (68 dwords; padding breaks bank pow2)
#define LOSS_OFF  8388608ull
#define ENC_OFF   8388609ull
#define PERP_OFF  75497473ull

__device__ __forceinline__ float tree8(float r0, float r1, float r2, float r3,
                                       float r4, float r5, float r6, float r7) {
    // numpy pairwise combine: ((r0+r1)+(r2+r3)) + ((r4+r5)+(r6+r7))
    return __fadd_rn(__fadd_rn(__fadd_rn(r0, r1), __fadd_rn(r2, r3)),
                     __fadd_rn(__fadd_rn(r4, r5), __fadd_rn(r6, r7)));
}

// Prep: ww[k] = sum(w[k]^2) in numpy pairwise order; zero counts + loss accumulator.
extern "C" __global__ __launch_bounds__(512)
void vq_prep(const float* __restrict__ w, float* __restrict__ ww,
             int* __restrict__ counts, float* __restrict__ lossAcc)
{
    const int k = threadIdx.x;                 // 512 threads
    const float* wk = w + k * DIM;
    float r[8];
    #pragma unroll
    for (int i = 0; i < 8; ++i) {
        #pragma unroll
        for (int j = 0; j < 8; ++j) {
            float v = wk[i * 8 + j];
            float pp = __fmul_rn(v, v);
            r[j] = (i == 0) ? pp : __fadd_rn(r[j], pp);
        }
    }
    ww[k] = tree8(r[0], r[1], r[2], r[3], r[4], r[5], r[6], r[7]);
    counts[k] = 0;
    if (k == 0) *lossAcc = 0.0f;
}

// Main kernel, R5: w-load latency amortization.
// R4 diagnosis: w streams via s_load from L2 (~250cyc/batch, 16 batches/iter,
// SGPRs can hold ~1 batch) with only 2 waves/SIMD -> ~2000cyc stall per
// 1200cyc iter, VALUBusy 32%. Fix: P=2 positions/thread (each w batch feeds
// 256 VALU-cyc >= L2 latency) and KB=8 codes/pass (one x ds_read feeds 64
// FMAs; DS pipe demand 41us < VALU 63us). 1 wave/SIMD; stalls hidden by ILP.
extern "C" __global__ __launch_bounds__(TB, 1)
void vq_main(const float* __restrict__ x, const float* __restrict__ w,
             const float* __restrict__ ww, float* __restrict__ out,
             int* __restrict__ counts, float* __restrict__ lossAcc)
{
    __shared__ float4 xls[TB * P * ROWD];      // 128 rows x 272 B = 34816 B
    __shared__ int    hcount[KCODES];
    __shared__ float  lred[TB];

    const int tid = threadIdx.x;
    const int n0  = blockIdx.x * (TB * P) + tid;   // position A; B = n0 + TB
    // 128 | 4096 -> both positions share the same image b.

    #pragma unroll
    for (int i = 0; i < 8; ++i) hcount[tid + i * TB] = 0;

    // ---- prologue per position: load x (channel stride HW), stash 2x in own
    // LDS row, build A = sum(x^2) replicating numpy pairwise_sum(64):
    // chunk c -> (i = c>>1, j = (c&1)*4+e); each r[j] sees i ascending.
    float A[P];
    #pragma unroll
    for (int p = 0; p < P; ++p) {
        const int n  = n0 + p * TB;
        const int b  = n >> 12;
        const int hw = n & 4095;
        const float* xp = x + ((size_t)b * DIM) * HW + hw;
        float4* xrow = &xls[(tid + p * TB) * ROWD];
        float r[8];
        #pragma unroll
        for (int c = 0; c < 16; ++c) {
            float v[4];
            #pragma unroll
            for (int e = 0; e < 4; ++e) v[e] = xp[(size_t)(4 * c + e) * HW];
            float4 ch;
            ch.x = v[0] + v[0]; ch.y = v[1] + v[1];     // exact doubling
            ch.z = v[2] + v[2]; ch.w = v[3] + v[3];
            xrow[c] = ch;                               // ds_write_b128, own row
            #pragma unroll
            for (int e = 0; e < 4; ++e) {
                const int j = (c & 1) * 4 + e;
                float pp = __fmul_rn(v[e], v[e]);
                if (c < 2) r[j] = pp;
                else       r[j] = __fadd_rn(r[j], pp);
            }
        }
        A[p] = tree8(r[0], r[1], r[2], r[3], r[4], r[5], r[6], r[7]);
    }

    // ---- argmin over codes, KB codes per pass, P positions per thread.
    float best[P];
    int   bestk[P];
    #pragma unroll
    for (int p = 0; p < P; ++p) { best[p] = INFINITY; bestk[p] = 0; }

    const size_t T0 = ENC_OFF + (size_t)blockIdx.x * (TB * P * KCODES); // 65536 dw/tile, T0%4==1
    float4* zs4 = reinterpret_cast<float4*>(out + T0 + 3);              // 16B-aligned
    const float4 zero4 = make_float4(0.0f, 0.0f, 0.0f, 0.0f);

    for (int k0 = 0; k0 < KCODES; k0 += KB) {      // 64 iters
        float acc[P][KB][8];
        const float* wp = w + (size_t)k0 * DIM;    // wave-uniform -> s_load path
        #pragma unroll
        for (int c = 0; c < 16; ++c) {
            float4 xc4[P];
            xc4[0] = xls[tid * ROWD + c];          // ds_read_b128
            xc4[1] = xls[(tid + TB) * ROWD + c];   // ds_read_b128
            #pragma unroll
            for (int kk = 0; kk < KB; ++kk) {
                const float* wk = wp + kk * DIM + 4 * c;
                #pragma unroll
                for (int e = 0; e < 4; ++e) {
                    const int j = (c & 1) * 4 + e;
                    const float we = wk[e];
                    #pragma unroll
                    for (int p = 0; p < P; ++p) {
                        const float xe = (e == 0) ? xc4[p].x : (e == 1) ? xc4[p].y
                                       : (e == 2) ? xc4[p].z : xc4[p].w;
                        if (c < 2) acc[p][kk][j] = __fmul_rn(xe, we);   // == fmaf(a,b,0)
                        else       acc[p][kk][j] = __fmaf_rn(xe, we, acc[p][kk][j]);
                    }
                }
            }
        }
        #pragma unroll
        for (int kk = 0; kk < KB; ++kk) {
            const float wwk = ww[k0 + kk];
            #pragma unroll
            for (int p = 0; p < P; ++p) {
                float dot  = tree8(acc[p][kk][0], acc[p][kk][1], acc[p][kk][2], acc[p][kk][3],
                                   acc[p][kk][4], acc[p][kk][5], acc[p][kk][6], acc[p][kk][7]);
                float t    = __fadd_rn(A[p], wwk);   // (||x||^2 + ||w_k||^2), ref order
                float dist = __fadd_rn(t, -dot);     // minus 2*x.w
                if (dist < best[p]) { best[p] = dist; bestk[p] = k0 + kk; }
            }
        }
        // coalesced zero-fill: 4 float4 per thread per iter, lanes contiguous
        const int m0 = (k0 >> 3) * (TB * 4) + tid;
        #pragma unroll
        for (int q = 0; q < 4; ++q) {
            const int m = m0 + q * TB;             // [0, 16384)
            if (m < 16383) zs4[m] = zero4;         // m=16383 crosses tile edge (OOB at last block)
        }
    }

    // edge dwords of this tile (not covered by the float4 sweep)
    if (tid < 3)   out[T0 + tid]   = 0.0f;         // d = 0,1,2
    if (tid == 3)  out[T0 + 65535] = 0.0f;         // d = 65535

    __syncthreads();   // vmcnt(0) drain of all zero stores; hcount init visible

    #pragma unroll
    for (int p = 0; p < P; ++p) {
        const int n = n0 + p * TB;
        out[ENC_OFF + (size_t)n * KCODES + bestk[p]] = 1.0f;  // one-hot after zeros
        atomicAdd(&hcount[bestk[p]], 1);
    }

    // ---- quantized output (transposed back) + SSE partial, both positions
    float sse = 0.0f;
    #pragma unroll
    for (int p = 0; p < P; ++p) {
        const int n  = n0 + p * TB;
        const int b  = n >> 12;
        const int hw = n & 4095;
        const float4* wrow = reinterpret_cast<const float4*>(w + (size_t)bestk[p] * DIM);
        float* qo = out + ((size_t)b * DIM) * HW + hw;
        float4* xrow = &xls[(tid + p * TB) * ROWD];
        #pragma unroll
        for (int c = 0; c < 16; ++c) {
            float4 q  = wrow[c];
            float4 xc = xrow[c];                   // 2x, so 0.5f* is exact
            qo[(size_t)(4 * c + 0) * HW] = q.x;
            qo[(size_t)(4 * c + 1) * HW] = q.y;
            qo[(size_t)(4 * c + 2) * HW] = q.z;
            qo[(size_t)(4 * c + 3) * HW] = q.w;
            float e0 = q.x - 0.5f * xc.x; sse = __fmaf_rn(e0, e0, sse);
            float e1 = q.y - 0.5f * xc.y; sse = __fmaf_rn(e1, e1, sse);
            float e2 = q.z - 0.5f * xc.z; sse = __fmaf_rn(e2, e2, sse);
            float e3 = q.w - 0.5f * xc.w; sse = __fmaf_rn(e3, e3, sse);
        }
    }
    lred[tid] = sse;
    __syncthreads();

    // histogram drain (after barrier: all hcount atomics done)
    #pragma unroll
    for (int i = 0; i < 8; ++i) {
        int c0 = hcount[tid + i * TB];
        if (c0) atomicAdd(&counts[tid + i * TB], c0);
    }

    // block loss reduction
    for (int s = TB / 2; s > 0; s >>= 1) {
        if (tid < s) lred[tid] += lred[tid + s];
        __syncthreads();
    }
    if (tid == 0) atomicAdd(lossAcc, lred[0]);
}

// Finalize: loss scalar + perplexity from histogram.
extern "C" __global__ __launch_bounds__(512)
void vq_finalize(const int* __restrict__ counts, const float* __restrict__ lossAcc,
                 float* __restrict__ out)
{
    __shared__ double sred[KCODES];
    const int t = threadIdx.x;                 // 512 threads
    double p = (double)counts[t] * (1.0 / (double)NPOS);
    sred[t] = -p * log(p + 1e-10);
    __syncthreads();
    for (int s = KCODES / 2; s > 0; s >>= 1) {
        if (t < s) sred[t] += sred[t + s];
        __syncthreads();
    }
    if (t == 0) {
        out[PERP_OFF] = (float)exp(sred[0]);
        out[LOSS_OFF] = 1.25f * (lossAcc[0] / 8388608.0f);
    }
}

extern "C" void kernel_launch(void* const* d_in, const int* in_sizes, int n_in,
                              void* d_out, int out_size, void* d_ws, size_t ws_size,
                              hipStream_t stream)
{
    const float* x = (const float*)d_in[0];    // [32,64,64,64] fp32
    const float* w = (const float*)d_in[1];    // [512,64] fp32
    float* out = (float*)d_out;

    float* ww      = (float*)d_ws;                         // 512 floats
    int*   counts  = (int*)((char*)d_ws + 2048);           // 512 ints
    float* lossAcc = (float*)((char*)d_ws + 4096);         // 1 float

    vq_prep<<<1, 512, 0, stream>>>(w, ww, counts, lossAcc);
    vq_main<<<NPOS / (TB * P), TB, 0, stream>>>(x, w, ww, out, counts, lossAcc);
    vq_finalize<<<1, 512, 0, stream>>>(counts, lossAcc, out);
}

// Round 6
// 450.169 us; speedup vs baseline: 2.2573x; 2.2573x over previous
//
#include <hip/hip_runtime.h>
#include <math.h>

// ---- problem constants ----
#define TB        256           // threads per block = 4 waves
#define POSB      64            // positions per block (1 per lane)
#define GROUPS    4             // K-split: wave g scans codes [g*KPG,(g+1)*KPG)
#define KPG       128           // codes per group
#define NPOS      131072        // B*H*W positions
#define KCODES    512
#define DIM       64
#define HW        4096          // H*W
#define LOSS_OFF  8388608ull
#define ENC_OFF   8388609ull
#define PERP_OFF  75497473ull

__device__ __forceinline__ float tree8(float r0, float r1, float r2, float r3,
                                       float r4, float r5, float r6, float r7) {
    // numpy pairwise combine: ((r0+r1)+(r2+r3)) + ((r4+r5)+(r6+r7))
    return __fadd_rn(__fadd_rn(__fadd_rn(r0, r1), __fadd_rn(r2, r3)),
                     __fadd_rn(__fadd_rn(r4, r5), __fadd_rn(r6, r7)));
}

// Prep: ww[k] = sum(w[k]^2) in numpy pairwise order; zero counts + loss accumulator.
extern "C" __global__ __launch_bounds__(512)
void vq_prep(const float* __restrict__ w, float* __restrict__ ww,
             int* __restrict__ counts, float* __restrict__ lossAcc)
{
    const int k = threadIdx.x;                 // 512 threads
    const float* wk = w + k * DIM;
    float r[8];
    #pragma unroll
    for (int i = 0; i < 8; ++i) {
        #pragma unroll
        for (int j = 0; j < 8; ++j) {
            float v = wk[i * 8 + j];
            float pp = __fmul_rn(v, v);
            r[j] = (i == 0) ? pp : __fadd_rn(r[j], pp);
        }
    }
    ww[k] = tree8(r[0], r[1], r[2], r[3], r[4], r[5], r[6], r[7]);
    counts[k] = 0;
    if (k == 0) *lossAcc = 0.0f;
}

// Main kernel, R6: K-split position-per-lane.
// R1-R5 shared flaw: inner loop mixed s_load(w) + ds_read(x) on one lgkmcnt
// counter at 2 waves/EU -> conservative waits serialized both queues,
// VALUBusy stuck ~27-32%. Here: x^2 in VGPRs (no DS in loop), w via
// wave-uniform s_load only, and 4-way K-split gives 8192 waves (32/CU
// grid-side). amdgpu_waves_per_eu(2,4): max=4 -> VGPR budget 128 >= ~95
// needed (launch_bounds min alone was ignored in R2; R5 spilled at 132).
extern "C" __global__ __launch_bounds__(TB)
__attribute__((amdgpu_waves_per_eu(2, 4)))
void vq_main(const float* __restrict__ x, const float* __restrict__ w,
             const float* __restrict__ ww, float* __restrict__ out,
             int* __restrict__ counts, float* __restrict__ lossAcc)
{
    __shared__ float cdist[GROUPS][POSB];
    __shared__ int   ckidx[GROUPS][POSB];
    __shared__ int   hcount[KCODES];

    const int tid = threadIdx.x;
    const int l   = tid & 63;                                  // lane = position slot
    const int g   = __builtin_amdgcn_readfirstlane(tid >> 6);  // wave id, provably uniform
    const int n   = blockIdx.x * POSB + l;                     // position (64|4096: one b per block)
    const int b   = n >> 12;
    const int hw  = n & 4095;

    hcount[tid]      = 0;
    hcount[tid + TB] = 0;

    // ---- prologue: x into VGPRs (channel stride HW), x2 = 2x, and
    // A = sum(x^2) replicating numpy pairwise_sum(64): r[j] over i ascending.
    // (All 4 waves load the same 16KB block slice -> L1 hits for 3 of 4.)
    const float* xp = x + ((size_t)b * DIM) * HW + hw;
    float x2[DIM];
    float r[8];
    #pragma unroll
    for (int i = 0; i < 8; ++i) {
        #pragma unroll
        for (int j = 0; j < 8; ++j) {
            const int d = i * 8 + j;
            float v = xp[(size_t)d * HW];
            x2[d] = v + v;                      // exact doubling
            float pp = __fmul_rn(v, v);
            r[j] = (i == 0) ? pp : __fadd_rn(r[j], pp);
        }
    }
    const float A = tree8(r[0], r[1], r[2], r[3], r[4], r[5], r[6], r[7]);

    // ---- scan my 128-code group; interleave coalesced float4 zero-fill of
    // the block's 64x512-dword encodings tile (T0%4==1, dwords 3+4m aligned).
    float best  = INFINITY;
    int   bestk = 0;
    const size_t T0 = ENC_OFF + (size_t)blockIdx.x * (POSB * KCODES);
    float4* zs4 = reinterpret_cast<float4*>(out + T0 + 3);
    const float4 zero4 = make_float4(0.0f, 0.0f, 0.0f, 0.0f);

    for (int kk = 0; kk < KPG; ++kk) {
        const int k = g * KPG + kk;             // wave-uniform -> s_load path
        const float* wk = w + (size_t)k * DIM;
        float s[8];
        #pragma unroll
        for (int i = 0; i < 8; ++i) {
            #pragma unroll
            for (int j = 0; j < 8; ++j) {
                const int d = i * 8 + j;
                if (i == 0) s[j] = __fmul_rn(x2[d], wk[d]);       // == fmaf(a,b,0)
                else        s[j] = __fmaf_rn(x2[d], wk[d], s[j]);
            }
        }
        float dot  = tree8(s[0], s[1], s[2], s[3], s[4], s[5], s[6], s[7]);
        float t    = __fadd_rn(A, ww[k]);       // (||x||^2 + ||w_k||^2), ref order
        float dist = __fadd_rn(t, -dot);        // minus 2*x.w
        if (dist < best) { best = dist; bestk = k; }

        if ((kk & 3) == 0) {                    // 32 float4 per thread total
            const int m = (kk >> 2) * TB + tid; // [0, 8192)
            if (m < 8191) zs4[m] = zero4;       // m=8191 crosses tile edge
        }
    }
    cdist[g][l] = best;
    ckidx[g][l] = bestk;

    // edge dwords of the tile (not covered by the float4 sweep)
    if (tid < 3)  out[T0 + tid]   = 0.0f;       // d = 0,1,2
    if (tid == 3) out[T0 + 32767] = 0.0f;       // d = 32767

    __syncthreads();   // zero stores drained (vmcnt(0) at barrier); candidates visible

    // ---- merge 4 candidates (ascending g = ascending k: ties keep first) ----
    float fb = cdist[0][l];
    int   fk = ckidx[0][l];
    #pragma unroll
    for (int gg = 1; gg < GROUPS; ++gg) {
        float dg = cdist[gg][l];
        int   kg = ckidx[gg][l];
        if (dg < fb) { fb = dg; fk = kg; }
    }

    // ---- epilogue: wave 0 only (constant x2 indices; avoids dynamic-index spill)
    if (g == 0) {
        out[ENC_OFF + (size_t)n * KCODES + fk] = 1.0f;   // one-hot after zeros
        atomicAdd(&hcount[fk], 1);

        const float4* wrow = reinterpret_cast<const float4*>(w + (size_t)fk * DIM);
        float* qo = out + ((size_t)b * DIM) * HW + hw;
        float sse = 0.0f;
        #pragma unroll
        for (int c = 0; c < 16; ++c) {
            float4 q = wrow[c];
            qo[(size_t)(4 * c + 0) * HW] = q.x;
            qo[(size_t)(4 * c + 1) * HW] = q.y;
            qo[(size_t)(4 * c + 2) * HW] = q.z;
            qo[(size_t)(4 * c + 3) * HW] = q.w;
            float e0 = q.x - 0.5f * x2[4 * c + 0]; sse = __fmaf_rn(e0, e0, sse);
            float e1 = q.y - 0.5f * x2[4 * c + 1]; sse = __fmaf_rn(e1, e1, sse);
            float e2 = q.z - 0.5f * x2[4 * c + 2]; sse = __fmaf_rn(e2, e2, sse);
            float e3 = q.w - 0.5f * x2[4 * c + 3]; sse = __fmaf_rn(e3, e3, sse);
        }
        // wave-level SSE reduction (64 lanes)
        #pragma unroll
        for (int off = 32; off > 0; off >>= 1) sse += __shfl_down(sse, off);
        if (l == 0) atomicAdd(lossAcc, sse);
    }

    __syncthreads();   // wave 0's hcount atomics done

    // histogram drain
    {
        int c0 = hcount[tid];       if (c0) atomicAdd(&counts[tid], c0);
        int c1 = hcount[tid + TB];  if (c1) atomicAdd(&counts[tid + TB], c1);
    }
}

// Finalize: loss scalar + perplexity from histogram.
extern "C" __global__ __launch_bounds__(512)
void vq_finalize(const int* __restrict__ counts, const float* __restrict__ lossAcc,
                 float* __restrict__ out)
{
    __shared__ double sred[KCODES];
    const int t = threadIdx.x;                 // 512 threads
    double p = (double)counts[t] * (1.0 / (double)NPOS);
    sred[t] = -p * log(p + 1e-10);
    __syncthreads();
    for (int s = KCODES / 2; s > 0; s >>= 1) {
        if (t < s) sred[t] += sred[t + s];
        __syncthreads();
    }
    if (t == 0) {
        out[PERP_OFF] = (float)exp(sred[0]);
        out[LOSS_OFF] = 1.25f * (lossAcc[0] / 8388608.0f);
    }
}

extern "C" void kernel_launch(void* const* d_in, const int* in_sizes, int n_in,
                              void* d_out, int out_size, void* d_ws, size_t ws_size,
                              hipStream_t stream)
{
    const float* x = (const float*)d_in[0];    // [32,64,64,64] fp32
    const float* w = (const float*)d_in[1];    // [512,64] fp32
    float* out = (float*)d_out;

    float* ww      = (float*)d_ws;                         // 512 floats
    int*   counts  = (int*)((char*)d_ws + 2048);           // 512 ints
    float* lossAcc = (float*)((char*)d_ws + 4096);         // 1 float

    vq_prep<<<1, 512, 0, stream>>>(w, ww, counts, lossAcc);
    vq_main<<<NPOS / POSB, TB, 0, stream>>>(x, w, ww, out, counts, lossAcc);
    vq_finalize<<<1, 512, 0, stream>>>(counts, lossAcc, out);
}